// Round 2
// baseline (560.372 us; speedup 1.0000x reference)
//
#include <hip/hip_runtime.h>

// Problem constants
#define H_ 96
#define W_ 96
#define HW 9216        // 96*96
#define C_ 64
#define OUTC 64
#define NPTS 9         // N = KS*KS
#define NCH 18         // 2*N offset channels
#define B_ 8
#define NPIX 73728     // B*H*W

// ---------------- Kernel A: offset field (3x3 conv, pad 1), c-split x4 ----------------
// Block: 256 threads = 4 channel-groups x 64 pixels. Each thread accumulates 18
// offset channels over its 16 input channels; LDS reduction over the 4 groups.
// Weights are read as wave-uniform scalar loads (group id forced to SGPR).
__global__ __launch_bounds__(256) void offs_kernel(
    const float* __restrict__ x, const float* __restrict__ w_off,
    const float* __restrict__ b_off, float* __restrict__ offs)
{
    __shared__ float s_red[4 * NCH * 64];   // 18.4 KB
    int t  = threadIdx.x;
    int pl = t & 63;
    int cg = __builtin_amdgcn_readfirstlane(t >> 6);  // wave-uniform group id

    int base = blockIdx.x * 64;      // 1152 blocks; 9216 % 64 == 0 -> b uniform
    int b    = base / HW;
    int rem0 = base - b * HW;
    int pix  = rem0 + pl;
    int i    = pix / W_;
    int j    = pix - i * W_;

    float acc[NCH];
#pragma unroll
    for (int ch = 0; ch < NCH; ++ch) acc[ch] = 0.0f;

    for (int cl = 0; cl < 16; ++cl) {
        int c = cg * 16 + cl;
        const float* xp = x + (b * C_ + c) * HW;
        float v[9];
#pragma unroll
        for (int u = 0; u < 3; ++u)
#pragma unroll
            for (int vv = 0; vv < 3; ++vv) {
                int ii = i + u - 1, jj = j + vv - 1;
                bool ok = (ii >= 0) & (ii < H_) & (jj >= 0) & (jj < W_);
                v[u * 3 + vv] = ok ? xp[ii * W_ + jj] : 0.0f;
            }
        // w_off[ch][c][uv] = w_off[(ch*C_ + c)*9 + uv]; uniform address -> s_load
        const float* wb = w_off + c * 9;
#pragma unroll
        for (int ch = 0; ch < NCH; ++ch) {
#pragma unroll
            for (int uv = 0; uv < 9; ++uv)
                acc[ch] += v[uv] * wb[ch * (C_ * 9) + uv];
        }
    }

#pragma unroll
    for (int ch = 0; ch < NCH; ++ch) s_red[(cg * NCH + ch) * 64 + pl] = acc[ch];
    __syncthreads();

    for (int idx = t; idx < NCH * 64; idx += 256) {
        int ch = idx >> 6, p = idx & 63;
        float s = s_red[ch * 64 + p]
                + s_red[(NCH + ch) * 64 + p]
                + s_red[(2 * NCH + ch) * 64 + p]
                + s_red[(3 * NCH + ch) * 64 + p];
        offs[(b * NCH + ch) * HW + rem0 + p] = s + b_off[ch];
    }
}

// ---------------- Kernel T: transpose w_ker into wk_t[k][oc], k = n*64 + c ----------------
__global__ __launch_bounds__(256) void wk_transpose(
    const float* __restrict__ w_ker, float* __restrict__ wk_t)
{
    int idx = blockIdx.x * 256 + threadIdx.x;  // 144*256 = 36864 exactly
    int oc = idx & 63;
    int kc = idx >> 6;       // n*64 + c
    int c  = kc & 63;
    int n  = kc >> 6;
    wk_t[idx] = w_ker[(oc * C_ + c) * 9 + n];
}

// ---------------- Kernel B: fused bilinear sample + GEMM, split-K x3 over n ----------------
// blockIdx.x: pixel tile (128 px). blockIdx.y = kg in 0..2: handles n = kg*3 .. kg*3+2.
// Partial results atomicAdd'ed into zero-initialized out; kg==0 adds bias.
__global__ __launch_bounds__(128) void deform_gemm(
    const float* __restrict__ x, const float* __restrict__ offs,
    const float* __restrict__ wk_t, const float* __restrict__ b_ker,
    float* __restrict__ out)
{
    __shared__ float s_val[32 * 128];  // [c_local][p]  16 KB
    __shared__ float s_wk [32 * 64];   // [c_local][oc]  8 KB

    int t    = threadIdx.x;
    int base = blockIdx.x * 128;       // 576 tiles; b uniform per tile
    int kg   = blockIdx.y;             // split-k group: rows kg-1 of the 3x3 kernel
    int b    = base / HW;
    int rem0 = base - b * HW;
    int pix  = rem0 + t;
    int i    = pix / W_;
    int j    = pix - i * W_;

    const float* xb = x + b * C_ * HW;

    float acc[8][8];
#pragma unroll
    for (int a = 0; a < 8; ++a)
#pragma unroll
        for (int bb = 0; bb < 8; ++bb) acc[a][bb] = 0.0f;

    for (int nn = 0; nn < 3; ++nn) {
        int n = kg * 3 + nn;
        // sampling coords for my pixel (p == t), reused over all 64 channels
        float offx = offs[(b * NCH + n) * HW + pix];
        float offy = offs[(b * NCH + NPTS + n) * HW + pix];
        float px = (float)(i + kg - 1) + offx;   // n/3 - 1 == kg - 1
        float py = (float)(j + nn - 1) + offy;   // n%3 - 1 == nn - 1
        float x0f = floorf(px), y0f = floorf(py);
        float lx = px - x0f, ly = py - y0f;
        int xi = (int)x0f, yi = (int)y0f;

        int a4[4]; float w4[4];
        float wx[2] = {1.0f - lx, lx};
        float wy[2] = {1.0f - ly, ly};
#pragma unroll
        for (int q = 0; q < 4; ++q) {
            int cx = xi + (q & 1);           // row
            int cy = yi + (q >> 1);          // col
            bool ok = (cx >= 0) & (cx < H_) & (cy >= 0) & (cy < W_);
            int ax = min(max(cx, 0), H_ - 1);
            int ay = min(max(cy, 0), W_ - 1);
            a4[q] = ax * W_ + ay;
            w4[q] = ok ? wx[q & 1] * wy[q >> 1] : 0.0f;
        }

        for (int ch = 0; ch < 2; ++ch) {
            __syncthreads();   // previous GEMM finished reading s_val/s_wk
            // stage 32x64 weight chunk (coalesced)
            const float* wsrc = wk_t + (n * 64 + ch * 32) * 64;
#pragma unroll
            for (int r = 0; r < 16; ++r) s_wk[r * 128 + t] = wsrc[r * 128 + t];
            // gather: lane = pixel, loop channels
            const float* xc = xb + (ch * 32) * HW;
#pragma unroll 4
            for (int c = 0; c < 32; ++c) {
                const float* xp = xc + c * HW;
                float v = w4[0] * xp[a4[0]] + w4[1] * xp[a4[1]]
                        + w4[2] * xp[a4[2]] + w4[3] * xp[a4[3]];
                s_val[c * 128 + t] = v;
            }
            __syncthreads();
            // GEMM: per-thread 8 pixels x 8 ocs
            int ocg = t & 7, pg = t >> 3;
#pragma unroll 2
            for (int k = 0; k < 32; ++k) {
                float4 s0 = *(const float4*)&s_val[k * 128 + pg * 8];
                float4 s1 = *(const float4*)&s_val[k * 128 + pg * 8 + 4];
                float4 w0 = *(const float4*)&s_wk [k * 64 + ocg * 8];
                float4 w1 = *(const float4*)&s_wk [k * 64 + ocg * 8 + 4];
                float sv[8] = {s0.x, s0.y, s0.z, s0.w, s1.x, s1.y, s1.z, s1.w};
                float wv[8] = {w0.x, w0.y, w0.z, w0.w, w1.x, w1.y, w1.z, w1.w};
#pragma unroll
                for (int pp = 0; pp < 8; ++pp)
#pragma unroll
                    for (int cc = 0; cc < 8; ++cc)
                        acc[pp][cc] += sv[pp] * wv[cc];
            }
        }
    }

    // epilogue: atomic accumulate (out zero-initialized); kg==0 adds bias
    int ocg = t & 7, pg = t >> 3;
#pragma unroll
    for (int cc = 0; cc < 8; ++cc) {
        int oc = ocg * 8 + cc;
        float bk = (kg == 0) ? b_ker[oc] : 0.0f;
        float* op = out + (b * OUTC + oc) * HW + rem0 + pg * 8;
#pragma unroll
        for (int e = 0; e < 8; ++e)
            atomicAdd(&op[e], acc[e][cc] + bk);
    }
}

extern "C" void kernel_launch(void* const* d_in, const int* in_sizes, int n_in,
                              void* d_out, int out_size, void* d_ws, size_t ws_size,
                              hipStream_t stream) {
    const float* x     = (const float*)d_in[0];
    const float* w_off = (const float*)d_in[1];
    const float* b_off = (const float*)d_in[2];
    const float* w_ker = (const float*)d_in[3];
    const float* b_ker = (const float*)d_in[4];
    float* out = (float*)d_out;

    float* ws   = (float*)d_ws;
    float* offs = ws;                 // 8*18*9216 = 1,327,104 floats (5.3 MB)
    float* wk_t = ws + 1327104;       // 36,864 floats

    offs_kernel <<<NPIX / 64, 256, 0, stream>>>(x, w_off, b_off, offs);
    wk_transpose<<<144,       256, 0, stream>>>(w_ker, wk_t);
    hipMemsetAsync(out, 0, (size_t)NPIX * OUTC * sizeof(float), stream);
    deform_gemm <<<dim3(NPIX / 128, 3), 128, 0, stream>>>(x, offs, wk_t, b_ker, out);
}

// Round 3
// 246.546 us; speedup vs baseline: 2.2729x; 2.2729x over previous
//
#include <hip/hip_runtime.h>

// Problem constants
#define H_ 96
#define W_ 96
#define HW 9216        // 96*96
#define C_ 64
#define OUTC 64
#define NPTS 9         // N = KS*KS
#define NCH 18         // 2*N offset channels
#define B_ 8
#define NPIX 73728     // B*H*W

typedef __attribute__((ext_vector_type(8))) short short8;   // 8 bf16 = 4 VGPRs
typedef __attribute__((ext_vector_type(4))) float f32x4;

__device__ __forceinline__ short f2bf(float f) {
    union { float f; unsigned u; } v; v.f = f;
    unsigned r = v.u + 0x7fffu + ((v.u >> 16) & 1u);   // RNE
    return (short)(r >> 16);
}

// ---------------- Kernel A: offset field (3x3 conv, pad 1), c-split x4 ----------------
__global__ __launch_bounds__(256) void offs_kernel(
    const float* __restrict__ x, const float* __restrict__ w_off,
    const float* __restrict__ b_off, float* __restrict__ offs)
{
    __shared__ float s_red[4 * NCH * 64];   // 18.4 KB
    int t  = threadIdx.x;
    int pl = t & 63;
    int cg = __builtin_amdgcn_readfirstlane(t >> 6);  // wave-uniform group id

    int base = blockIdx.x * 64;      // 1152 blocks; b uniform
    int b    = base / HW;
    int rem0 = base - b * HW;
    int pix  = rem0 + pl;
    int i    = pix / W_;
    int j    = pix - i * W_;

    float acc[NCH];
#pragma unroll
    for (int ch = 0; ch < NCH; ++ch) acc[ch] = 0.0f;

    for (int cl = 0; cl < 16; ++cl) {
        int c = cg * 16 + cl;
        const float* xp = x + (b * C_ + c) * HW;
        float v[9];
#pragma unroll
        for (int u = 0; u < 3; ++u)
#pragma unroll
            for (int vv = 0; vv < 3; ++vv) {
                int ii = i + u - 1, jj = j + vv - 1;
                bool ok = (ii >= 0) & (ii < H_) & (jj >= 0) & (jj < W_);
                v[u * 3 + vv] = ok ? xp[ii * W_ + jj] : 0.0f;
            }
        const float* wb = w_off + c * 9;   // wave-uniform -> s_load
#pragma unroll
        for (int ch = 0; ch < NCH; ++ch) {
#pragma unroll
            for (int uv = 0; uv < 9; ++uv)
                acc[ch] += v[uv] * wb[ch * (C_ * 9) + uv];
        }
    }

#pragma unroll
    for (int ch = 0; ch < NCH; ++ch) s_red[(cg * NCH + ch) * 64 + pl] = acc[ch];
    __syncthreads();

    for (int idx = t; idx < NCH * 64; idx += 256) {
        int ch = idx >> 6, p = idx & 63;
        float s = s_red[ch * 64 + p]
                + s_red[(NCH + ch) * 64 + p]
                + s_red[(2 * NCH + ch) * 64 + p]
                + s_red[(3 * NCH + ch) * 64 + p];
        offs[(b * NCH + ch) * HW + rem0 + p] = s + b_off[ch];
    }
}

// ---------------- Kernel T: w_ker -> bf16 B-fragment layout ----------------
// Frag storage: flat bf16 index = ((sg*4 + nt)*512) + l*8 + j,  sg = g*6+s in [0,18)
// Element = B[k][oc] with k_local = nl*64 + c, nl = s>>1, c = (s&1)*32 + (l>>4)*8 + j,
//           oc = nt*16 + (l&15), kernel tap n = g*3 + nl.
__global__ __launch_bounds__(256) void wk_frag_kernel(
    const float* __restrict__ w_ker, short* __restrict__ wk_frag)
{
    int idx = blockIdx.x * 256 + threadIdx.x;   // 144*256 = 36864 exactly
    int jj = idx & 7;
    int l  = (idx >> 3) & 63;
    int nt = (idx >> 9) & 3;
    int sg = idx >> 11;                // g*6 + s
    int g  = sg / 6;
    int s  = sg - g * 6;
    int nl = s >> 1;
    int c  = (s & 1) * 32 + (l >> 4) * 8 + jj;
    int oc = nt * 16 + (l & 15);
    wk_frag[idx] = f2bf(w_ker[(oc * C_ + c) * 9 + g * 3 + nl]);
}

// ---------------- Kernel B: fused bilinear sample + MFMA GEMM ----------------
// Block: 256 thr (4 waves), 64-px tile, all 64 oc, K=576 in 3 n-groups of 192.
// A staged in LDS in MFMA A-frag layout (bf16); B-frags read from global (L1-hot).
__global__ __launch_bounds__(256, 4) void deform_mfma(
    const float* __restrict__ x, const float* __restrict__ offs,
    const short* __restrict__ wk_frag, const float* __restrict__ b_ker,
    float* __restrict__ out)
{
    // union: A-frag area (64px*192k bf16 = 24576 B)  /  out-stage (64*68 f32 = 17408 B)
    __shared__ __align__(16) char smem_raw[24576];
    short* sA   = (short*)smem_raw;
    float* sOut = (float*)smem_raw;

    int t    = threadIdx.x;
    int lane = t & 63;
    int wv   = t >> 6;          // wave id == m-tile  (also sampling c-group)
    int cg   = wv;

    int base = blockIdx.x * 64;   // 1152 blocks; b uniform per block
    int b    = base / HW;
    int rem0 = base - b * HW;
    int pxl  = t & 63;            // my pixel within tile (same for all 4 c-groups)
    int pix  = rem0 + pxl;
    int i    = pix / W_;
    int j    = pix - i * W_;

    const float* xb = x + b * C_ * HW;

    f32x4 acc[4];
#pragma unroll
    for (int nt = 0; nt < 4; ++nt) acc[nt] = (f32x4){0.f, 0.f, 0.f, 0.f};

    for (int g = 0; g < 3; ++g) {
        // ---- sample phase: 3 taps x 16 channels -> bf16 A-frags in LDS ----
#pragma unroll
        for (int nl = 0; nl < 3; ++nl) {
            int n = g * 3 + nl;
            float offx = offs[(b * NCH + n) * HW + pix];
            float offy = offs[(b * NCH + NPTS + n) * HW + pix];
            float px = (float)(i + g - 1) + offx;
            float py = (float)(j + nl - 1) + offy;
            float x0f = floorf(px), y0f = floorf(py);
            float lx = px - x0f, ly = py - y0f;
            int xi = (int)x0f, yi = (int)y0f;

            int a4[4]; float w4[4];
            float wx[2] = {1.0f - lx, lx};
            float wy[2] = {1.0f - ly, ly};
#pragma unroll
            for (int q = 0; q < 4; ++q) {
                int cx = xi + (q & 1);
                int cy = yi + (q >> 1);
                bool ok = (cx >= 0) & (cx < H_) & (cy >= 0) & (cy < W_);
                int ax = min(max(cx, 0), H_ - 1);
                int ay = min(max(cy, 0), W_ - 1);
                a4[q] = ax * W_ + ay;
                w4[q] = ok ? wx[q & 1] * wy[q >> 1] : 0.0f;
            }

            int s = nl * 2 + (cg >> 1);            // local k-step
#pragma unroll
            for (int q2 = 0; q2 < 2; ++q2) {
                int l = (pxl & 15) | (((cg & 1) * 2 + q2) << 4);
                short8 pk;
#pragma unroll
                for (int e = 0; e < 8; ++e) {
                    int c = cg * 16 + q2 * 8 + e;
                    const float* xp = xb + c * HW;
                    float v = w4[0] * xp[a4[0]] + w4[1] * xp[a4[1]]
                            + w4[2] * xp[a4[2]] + w4[3] * xp[a4[3]];
                    pk[e] = f2bf(v);
                }
                *(short8*)(&sA[(((pxl >> 4) * 6 + s) << 9) + l * 8]) = pk;
            }
        }
        __syncthreads();
        // ---- MFMA phase: 6 k-steps x 4 oc-tiles ----
#pragma unroll
        for (int s = 0; s < 6; ++s) {
            short8 a = *(const short8*)(&sA[((wv * 6 + s) << 9) + lane * 8]);
            const short* wb = wk_frag + (((g * 6 + s) * 4) << 9) + lane * 8;
#pragma unroll
            for (int nt = 0; nt < 4; ++nt) {
                short8 bf = *(const short8*)(wb + (nt << 9));
                acc[nt] = __builtin_amdgcn_mfma_f32_16x16x32_bf16(a, bf, acc[nt], 0, 0, 0);
            }
        }
        __syncthreads();   // protect sA before next group's sampler (and sOut reuse)
    }

    // ---- epilogue: C-frags -> padded LDS -> coalesced float4 stores ----
    int colc = lane & 15, rowq = lane >> 4;
#pragma unroll
    for (int nt = 0; nt < 4; ++nt) {
        int oc = nt * 16 + colc;
        float bias = b_ker[oc];
#pragma unroll
        for (int r = 0; r < 4; ++r) {
            int p = wv * 16 + rowq * 4 + r;     // C/D: col=lane&15, row=(lane>>4)*4+reg
            sOut[p * 68 + oc] = acc[nt][r] + bias;
        }
    }
    __syncthreads();

    int oc = t >> 2, pq = t & 3;
    float* op = out + (b * OUTC + oc) * HW + rem0;
#pragma unroll
    for (int e2 = 0; e2 < 4; ++e2) {
        int p0 = pq * 4 + e2 * 16;
        float4 v = make_float4(sOut[(p0 + 0) * 68 + oc], sOut[(p0 + 1) * 68 + oc],
                               sOut[(p0 + 2) * 68 + oc], sOut[(p0 + 3) * 68 + oc]);
        *(float4*)(op + p0) = v;
    }
}

extern "C" void kernel_launch(void* const* d_in, const int* in_sizes, int n_in,
                              void* d_out, int out_size, void* d_ws, size_t ws_size,
                              hipStream_t stream) {
    const float* x     = (const float*)d_in[0];
    const float* w_off = (const float*)d_in[1];
    const float* b_off = (const float*)d_in[2];
    const float* w_ker = (const float*)d_in[3];
    const float* b_ker = (const float*)d_in[4];
    float* out = (float*)d_out;

    float* ws      = (float*)d_ws;
    float* offs    = ws;                        // 1,327,104 floats (5.3 MB)
    short* wk_frag = (short*)(ws + 1327104);    // 36,864 bf16 (72 KB)

    offs_kernel   <<<NPIX / 64, 256, 0, stream>>>(x, w_off, b_off, offs);
    wk_frag_kernel<<<144,       256, 0, stream>>>(w_ker, wk_frag);
    deform_mfma   <<<NPIX / 64, 256, 0, stream>>>(x, offs, wk_frag, b_ker, out);
}